// Round 1
// baseline (55552.307 us; speedup 1.0000x reference)
//
#include <hip/hip_runtime.h>
#include <hip/hip_cooperative_groups.h>
#include <stdint.h>

namespace cg = cooperative_groups;

#define B_  32
#define T_  1024
#define I_  512
#define H_  1024
#define C_  512
#define G4H 4096
#define NWG 128

typedef __bf16 bf16x8 __attribute__((ext_vector_type(8)));
typedef float  f32x4  __attribute__((ext_vector_type(4)));

__device__ __forceinline__ unsigned short f2bf(float f) {
    uint32_t b = __float_as_uint(f);
    b = (b + 0x7FFFu + ((b >> 16) & 1u)) >> 16;
    return (unsigned short)b;
}
__device__ __forceinline__ float sigf(float x)   { return 1.0f / (1.0f + __expf(-x)); }
__device__ __forceinline__ float tanh_f(float x) { return 2.0f / (1.0f + __expf(-2.0f * x)) - 1.0f; }

// ---------------- fp32 -> bf16 conversion (vectorized x4) ----------------
__global__ void cvt_kernel(const float* __restrict__ src, unsigned short* __restrict__ dst, int n4) {
    int i = blockIdx.x * blockDim.x + threadIdx.x;
    if (i < n4) {
        float4 v = ((const float4*)src)[i];
        ushort4 o;
        o.x = f2bf(v.x); o.y = f2bf(v.y); o.z = f2bf(v.z); o.w = f2bf(v.w);
        ((ushort4*)dst)[i] = o;
    }
}

__global__ void bias_kernel(const float* __restrict__ a, const float* __restrict__ b, float* __restrict__ o) {
    int i = blockIdx.x * blockDim.x + threadIdx.x;
    if (i < G4H) o[i] = a[i] + b[i];
}

// ---------------- persistent cooperative LSTM recurrence ----------------
// 128 WGs x 512 threads. WG wg owns hidden units j in [wg*8, wg*8+8).
// LDS: W slice [32 cols][1536 K] bf16 (K = 1024 h-part + 512 x-part), XOR-swizzled
// by 16B granule: granule g stored at g ^ (col & 7).
// 8 waves k-split K=1536 (192 each = 6 MFMA k-steps of 32).
__global__ __launch_bounds__(512, 1) void lstm_rec(
        const unsigned short* __restrict__ whh,   // [4096][1024] bf16
        const unsigned short* __restrict__ wih,   // [4096][512]  bf16
        const unsigned short* __restrict__ xb,    // [32][1024][512] bf16
        const float* __restrict__ bias,           // [4096] (b_ih + b_hh)
        unsigned short* __restrict__ hall)        // [1025][32][1024] bf16
{
    extern __shared__ char smem[];
    unsigned short* Wlds   = (unsigned short*)smem;              // 32*1536*2 = 98304 B
    float*          scratch = (float*)(smem + 98304);            // [8][32][32] = 32768 B
    float*          biasl   = (float*)(smem + 98304 + 32768);    // 32 floats

    const int tid  = threadIdx.x;
    const int wg   = blockIdx.x;
    const int lane = tid & 63;
    const int wq   = tid >> 6;          // wave id 0..7 = k-split index
    const int l15  = lane & 15;
    const int l4   = lane >> 4;

    // ---- one-time: stage W slice into LDS (swizzled) ----
    for (int s = tid; s < 32 * 192; s += 512) {
        int col = s / 192, g = s % 192;
        int grow = (col >> 3) * H_ + wg * 8 + (col & 7);   // global gate row
        const unsigned short* src = (g < 128) ? (whh + grow * H_ + g * 8)
                                              : (wih + grow * I_ + (g - 128) * 8);
        int4 v = *(const int4*)src;
        int gd = g ^ (col & 7);
        *(int4*)(Wlds + col * 1536 + gd * 8) = v;
    }
    if (tid < 32)
        biasl[tid] = bias[(tid >> 3) * H_ + wg * 8 + (tid & 7)];
    // zero h slot 0
    {
        int gtid = wg * 512 + tid;
        if (gtid < B_ * H_) hall[gtid] = 0;
    }
    float c_state = 0.0f;

    cg::grid_group grid = cg::this_grid();
    __threadfence();
    grid.sync();
    __threadfence();

    for (int t = 0; t < T_; ++t) {
        const unsigned short* hprev = hall + t * (B_ * H_);

        f32x4 acc[2][2];
        #pragma unroll
        for (int a = 0; a < 2; a++)
            #pragma unroll
            for (int b = 0; b < 2; b++) acc[a][b] = (f32x4){0.f, 0.f, 0.f, 0.f};

        #pragma unroll
        for (int ks = 0; ks < 6; ks++) {
            int kbase = wq * 192 + ks * 32;
            int kk = kbase + l4 * 8;                 // this lane's 8-elem k start
            bf16x8 af[2];
            #pragma unroll
            for (int mt = 0; mt < 2; mt++) {
                int bb = mt * 16 + l15;
                const unsigned short* sp = (kk < H_)
                    ? (hprev + bb * H_ + kk)
                    : (xb + (bb * T_ + t) * I_ + (kk - H_));
                af[mt] = *(const bf16x8*)sp;
            }
            int gb = kbase >> 3;
            bf16x8 bfr[2];
            #pragma unroll
            for (int nt = 0; nt < 2; nt++) {
                int col = nt * 16 + l15;
                int gg = (gb + l4) ^ (col & 7);
                bfr[nt] = *(const bf16x8*)(Wlds + col * 1536 + gg * 8);
            }
            #pragma unroll
            for (int mt = 0; mt < 2; mt++)
                #pragma unroll
                for (int nt = 0; nt < 2; nt++)
                    acc[mt][nt] = __builtin_amdgcn_mfma_f32_16x16x32_bf16(af[mt], bfr[nt], acc[mt][nt], 0, 0, 0);
        }

        // partial results -> LDS scratch
        #pragma unroll
        for (int mt = 0; mt < 2; mt++)
            #pragma unroll
            for (int nt = 0; nt < 2; nt++)
                #pragma unroll
                for (int r = 0; r < 4; r++) {
                    int bb  = mt * 16 + l4 * 4 + r;       // batch (D row)
                    int col = nt * 16 + l15;              // gate col (D col)
                    scratch[(wq * 32 + bb) * 32 + col] = acc[mt][nt][r];
                }
        __syncthreads();

        // pointwise LSTM cell: 256 threads = 32 batches x 8 units
        if (tid < 256) {
            int bb = tid >> 3, u = tid & 7;
            float p0 = biasl[u], p1 = biasl[8 + u], p2 = biasl[16 + u], p3 = biasl[24 + u];
            #pragma unroll
            for (int q = 0; q < 8; q++) {
                const float* sc = scratch + (q * 32 + bb) * 32;
                p0 += sc[u]; p1 += sc[8 + u]; p2 += sc[16 + u]; p3 += sc[24 + u];
            }
            float ig = sigf(p0), fg = sigf(p1), gg = tanh_f(p2), og = sigf(p3);
            c_state = fg * c_state + ig * gg;
            float h = og * tanh_f(c_state);
            hall[((t + 1) * B_ + bb) * H_ + wg * 8 + u] = f2bf(h);
        }
        __threadfence();
        grid.sync();
        __threadfence();
    }
}

// ---------------- output GEMMs: C[M x N] = A[M x 1024] * B[N x 1024]^T + bias ----------------
// 128x128 tile, BK=64, 4 waves (2x2), reg-staged LDS with XOR swizzle.
// PERM 1: out[b][t][c] (N=512, row r = t*32+b). PERM 2: row-major N=1024.
template<int PERM>
__global__ __launch_bounds__(256) void gemm_bt(
        const unsigned short* __restrict__ A,
        const unsigned short* __restrict__ Bw,
        const float* __restrict__ bias,
        float* __restrict__ out)
{
    __shared__ unsigned short As[128 * 64];
    __shared__ unsigned short Bs[128 * 64];
    const int tid  = threadIdx.x;
    const int lane = tid & 63, w = tid >> 6;
    const int wm = w >> 1, wn = w & 1;
    const int mbase = blockIdx.y * 128, nbase = blockIdx.x * 128;
    const int l15 = lane & 15, l4 = lane >> 4;

    f32x4 acc[4][4];
    #pragma unroll
    for (int i = 0; i < 4; i++)
        #pragma unroll
        for (int j = 0; j < 4; j++) acc[i][j] = (f32x4){0.f, 0.f, 0.f, 0.f};

    for (int kb = 0; kb < 16; kb++) {
        __syncthreads();
        #pragma unroll
        for (int i = 0; i < 4; i++) {
            int s = i * 256 + tid;
            int row = s >> 3, g = s & 7;
            int gd = g ^ (row & 7);
            int4 va = *(const int4*)(A  + (mbase + row) * 1024 + kb * 64 + g * 8);
            *(int4*)(As + row * 64 + gd * 8) = va;
            int4 vb = *(const int4*)(Bw + (nbase + row) * 1024 + kb * 64 + g * 8);
            *(int4*)(Bs + row * 64 + gd * 8) = vb;
        }
        __syncthreads();
        #pragma unroll
        for (int kk = 0; kk < 2; kk++) {
            bf16x8 af[4], bf[4];
            #pragma unroll
            for (int mt = 0; mt < 4; mt++) {
                int row = wm * 64 + mt * 16 + l15;
                int gg = (kk * 4 + l4) ^ (row & 7);
                af[mt] = *(const bf16x8*)(As + row * 64 + gg * 8);
            }
            #pragma unroll
            for (int nt = 0; nt < 4; nt++) {
                int row = wn * 64 + nt * 16 + l15;
                int gg = (kk * 4 + l4) ^ (row & 7);
                bf[nt] = *(const bf16x8*)(Bs + row * 64 + gg * 8);
            }
            #pragma unroll
            for (int mt = 0; mt < 4; mt++)
                #pragma unroll
                for (int nt = 0; nt < 4; nt++)
                    acc[mt][nt] = __builtin_amdgcn_mfma_f32_16x16x32_bf16(af[mt], bf[nt], acc[mt][nt], 0, 0, 0);
        }
    }
    #pragma unroll
    for (int mt = 0; mt < 4; mt++)
        #pragma unroll
        for (int nt = 0; nt < 4; nt++)
            #pragma unroll
            for (int r = 0; r < 4; r++) {
                int grow = mbase + wm * 64 + mt * 16 + l4 * 4 + r;
                int gcol = nbase + wn * 64 + nt * 16 + l15;
                float v = acc[mt][nt][r] + bias[gcol];
                int idx;
                if (PERM == 1) {
                    int tt = grow >> 5, bb = grow & 31;
                    idx = (bb * 1024 + tt) * 512 + gcol;
                } else {
                    idx = grow * 1024 + gcol;
                }
                out[idx] = v;
            }
}

// ---------------- host ----------------
extern "C" void kernel_launch(void* const* d_in, const int* in_sizes, int n_in,
                              void* d_out, int out_size, void* d_ws, size_t ws_size,
                              hipStream_t stream) {
    (void)in_sizes; (void)n_in; (void)out_size; (void)ws_size;
    const float* x    = (const float*)d_in[0];
    const float* Wih  = (const float*)d_in[1];
    const float* Whh  = (const float*)d_in[2];
    const float* bih  = (const float*)d_in[3];
    const float* bhh  = (const float*)d_in[4];
    const float* fcw  = (const float*)d_in[5];
    const float* fcb  = (const float*)d_in[6];
    const float* lnw  = (const float*)d_in[7];
    const float* lnb  = (const float*)d_in[8];
    float* out = (float*)d_out;

    char* ws = (char*)d_ws;
    size_t o = 0;
    unsigned short* whh_b = (unsigned short*)(ws + o); o += 8388608;   // [4096][1024]
    unsigned short* wih_b = (unsigned short*)(ws + o); o += 4194304;   // [4096][512]
    unsigned short* fcw_b = (unsigned short*)(ws + o); o += 1048576;   // [512][1024]
    unsigned short* lnw_b = (unsigned short*)(ws + o); o += 2097152;   // [1024][1024]
    unsigned short* x_b   = (unsigned short*)(ws + o); o += 33554432;  // [32][1024][512]
    float*          bias_c = (float*)(ws + o);         o += 16384;     // [4096]
    unsigned short* hall  = (unsigned short*)(ws + o); o += 67174400;  // [1025][32][1024]

    cvt_kernel<<<4096,  256, 0, stream>>>(Whh, whh_b, 4194304 / 4);
    cvt_kernel<<<2048,  256, 0, stream>>>(Wih, wih_b, 2097152 / 4);
    cvt_kernel<<<512,   256, 0, stream>>>(fcw, fcw_b, 524288 / 4);
    cvt_kernel<<<1024,  256, 0, stream>>>(lnw, lnw_b, 1048576 / 4);
    cvt_kernel<<<16384, 256, 0, stream>>>(x,   x_b,   16777216 / 4);
    bias_kernel<<<16, 256, 0, stream>>>(bih, bhh, bias_c);

    const unsigned short* a0 = whh_b;
    const unsigned short* a1 = wih_b;
    const unsigned short* a2 = x_b;
    const float*          a3 = bias_c;
    unsigned short*       a4 = hall;
    void* args[5] = { (void*)&a0, (void*)&a1, (void*)&a2, (void*)&a3, (void*)&a4 };
    hipLaunchCooperativeKernel((void*)lstm_rec, dim3(NWG), dim3(512), args,
                               (unsigned)(98304 + 32768 + 128), stream);

    const unsigned short* hseq = hall + 32768;  // slot 1 = h at t=0
    gemm_bt<1><<<dim3(4, 256), 256, 0, stream>>>(hseq, fcw_b, fcb, out);
    gemm_bt<2><<<dim3(8, 256), 256, 0, stream>>>(hseq, lnw_b, lnb, out + 16777216);
}

// Round 2
// 4573.798 us; speedup vs baseline: 12.1458x; 12.1458x over previous
//
#include <hip/hip_runtime.h>
#include <stdint.h>

#define B_  32
#define T_  1024
#define I_  512
#define H_  1024
#define C_  512
#define G4H 4096
#define NWG 128

typedef __bf16 bf16x8 __attribute__((ext_vector_type(8)));
typedef float  f32x4  __attribute__((ext_vector_type(4)));
typedef unsigned long long u64;

__device__ __forceinline__ unsigned short f2bf(float f) {
    uint32_t b = __float_as_uint(f);
    b = (b + 0x7FFFu + ((b >> 16) & 1u)) >> 16;
    return (unsigned short)b;
}
__device__ __forceinline__ float sigf(float x)   { return 1.0f / (1.0f + __expf(-x)); }
__device__ __forceinline__ float tanh_f(float x) { return 2.0f / (1.0f + __expf(-2.0f * x)) - 1.0f; }

// ---------------- fp32 -> bf16 conversion (vectorized x4) ----------------
__global__ void cvt_kernel(const float* __restrict__ src, unsigned short* __restrict__ dst, int n4) {
    int i = blockIdx.x * blockDim.x + threadIdx.x;
    if (i < n4) {
        float4 v = ((const float4*)src)[i];
        ushort4 o;
        o.x = f2bf(v.x); o.y = f2bf(v.y); o.z = f2bf(v.z); o.w = f2bf(v.w);
        ((ushort4*)dst)[i] = o;
    }
}

__global__ void bias_kernel(const float* __restrict__ a, const float* __restrict__ b, float* __restrict__ o) {
    int i = blockIdx.x * blockDim.x + threadIdx.x;
    if (i < G4H) o[i] = a[i] + b[i];
}

// ---------------- persistent LSTM recurrence, flag-based dataflow sync ----------------
// 128 WGs x 512 threads (cooperative launch for co-residency; NO grid.sync).
// WG wg owns hidden units [wg*8, wg*8+8) -> 32 gate columns.
// LDS W slice: [32 cols][1536 K] bf16, XOR-swizzled by 16B granule (g ^ (col&7)).
// K split per wave wq: h-K [wq*128, +128) (4 mfma k-steps), x-K [wq*64, +64) (2 k-steps).
// Cross-WG h exchange: producers store h via agent-scope (L2-bypass) 8B atomics ->
// LLC-coherent; per-WG per-step ready flag; consumers spin on flags, then plain loads.
__global__ __launch_bounds__(512, 1) void lstm_rec(
        const unsigned short* __restrict__ whh,   // [4096][1024] bf16
        const unsigned short* __restrict__ wih,   // [4096][512]  bf16
        const unsigned short* __restrict__ xb,    // [32][1024][512] bf16
        const float* __restrict__ bias,           // [4096] (b_ih + b_hh)
        unsigned short* __restrict__ hall,        // [1025][32][1024] bf16 (slot 0 pre-zeroed)
        unsigned int* __restrict__ flags)         // [1024][128] (pre-zeroed)
{
    extern __shared__ char smem[];
    unsigned short* Wlds    = (unsigned short*)smem;                     // 98304 B
    float*          scratch = (float*)(smem + 98304);                    // 32768 B
    float*          biasl   = (float*)(smem + 98304 + 32768);            // 128 B
    unsigned short* hstage  = (unsigned short*)(smem + 98304 + 32768 + 128); // 512 B

    const int tid  = threadIdx.x;
    const int wg   = blockIdx.x;
    const int lane = tid & 63;
    const int wq   = tid >> 6;          // wave id 0..7
    const int l15  = lane & 15;
    const int l4   = lane >> 4;

    // ---- one-time: stage W slice into LDS (swizzled) ----
    for (int s = tid; s < 32 * 192; s += 512) {
        int col = s / 192, g = s % 192;
        int grow = (col >> 3) * H_ + wg * 8 + (col & 7);   // global gate row
        const unsigned short* src = (g < 128) ? (whh + grow * H_ + g * 8)
                                              : (wih + grow * I_ + (g - 128) * 8);
        int4 v = *(const int4*)src;
        int gd = g ^ (col & 7);
        *(int4*)(Wlds + col * 1536 + gd * 8) = v;
    }
    if (tid < 32)
        biasl[tid] = bias[(tid >> 3) * H_ + wg * 8 + (tid & 7)];
    __syncthreads();

    float c_state = 0.0f;

    for (int t = 0; t < T_; ++t) {
        f32x4 acc[2][2];
        #pragma unroll
        for (int a = 0; a < 2; a++)
            #pragma unroll
            for (int b = 0; b < 2; b++) acc[a][b] = (f32x4){0.f, 0.f, 0.f, 0.f};

        // ---- x-part first: no dependency on h_t, hides producer latency ----
        #pragma unroll
        for (int kxs = 0; kxs < 2; kxs++) {
            int kk = wq * 64 + kxs * 32 + l4 * 8;      // x-K local [0,512)
            bf16x8 af[2];
            #pragma unroll
            for (int mt = 0; mt < 2; mt++) {
                int bb = mt * 16 + l15;
                af[mt] = *(const bf16x8*)(xb + (bb * T_ + t) * I_ + kk);
            }
            int gbase = 128 + (kk >> 3);               // x granules at 128..191
            bf16x8 bfr[2];
            #pragma unroll
            for (int nt = 0; nt < 2; nt++) {
                int col = nt * 16 + l15;
                int gg = gbase ^ (col & 7);
                bfr[nt] = *(const bf16x8*)(Wlds + col * 1536 + gg * 8);
            }
            #pragma unroll
            for (int mt = 0; mt < 2; mt++)
                #pragma unroll
                for (int nt = 0; nt < 2; nt++)
                    acc[mt][nt] = __builtin_amdgcn_mfma_f32_16x16x32_bf16(af[mt], bfr[nt], acc[mt][nt], 0, 0, 0);
        }

        // ---- wait for all h_t slices (slot t) ----
        if (t > 0) {
            if (tid < NWG) {
                unsigned int* f = flags + (t - 1) * NWG + tid;
                while (__hip_atomic_load(f, __ATOMIC_RELAXED, __HIP_MEMORY_SCOPE_AGENT) == 0u)
                    __builtin_amdgcn_s_sleep(1);
            }
            __syncthreads();
            asm volatile("" ::: "memory");
        }

        // ---- h-part ----
        const unsigned short* hprev = hall + (size_t)t * (B_ * H_);
        #pragma unroll
        for (int khs = 0; khs < 4; khs++) {
            int kk = wq * 128 + khs * 32 + l4 * 8;     // h-K [0,1024)
            bf16x8 af[2];
            #pragma unroll
            for (int mt = 0; mt < 2; mt++) {
                int bb = mt * 16 + l15;
                af[mt] = *(const bf16x8*)(hprev + bb * H_ + kk);
            }
            int gbase = kk >> 3;
            bf16x8 bfr[2];
            #pragma unroll
            for (int nt = 0; nt < 2; nt++) {
                int col = nt * 16 + l15;
                int gg = gbase ^ (col & 7);
                bfr[nt] = *(const bf16x8*)(Wlds + col * 1536 + gg * 8);
            }
            #pragma unroll
            for (int mt = 0; mt < 2; mt++)
                #pragma unroll
                for (int nt = 0; nt < 2; nt++)
                    acc[mt][nt] = __builtin_amdgcn_mfma_f32_16x16x32_bf16(af[mt], bfr[nt], acc[mt][nt], 0, 0, 0);
        }

        // ---- partial results -> LDS scratch ----
        #pragma unroll
        for (int mt = 0; mt < 2; mt++)
            #pragma unroll
            for (int nt = 0; nt < 2; nt++)
                #pragma unroll
                for (int r = 0; r < 4; r++) {
                    int bb  = mt * 16 + l4 * 4 + r;
                    int col = nt * 16 + l15;
                    scratch[(wq * 32 + bb) * 32 + col] = acc[mt][nt][r];
                }
        __syncthreads();

        // ---- pointwise LSTM cell: 256 threads = 32 batches x 8 units ----
        if (tid < 256) {
            int bb = tid >> 3, u = tid & 7;
            float p0 = biasl[u], p1 = biasl[8 + u], p2 = biasl[16 + u], p3 = biasl[24 + u];
            #pragma unroll
            for (int q = 0; q < 8; q++) {
                const float* sc = scratch + (q * 32 + bb) * 32;
                p0 += sc[u]; p1 += sc[8 + u]; p2 += sc[16 + u]; p3 += sc[24 + u];
            }
            float ig = sigf(p0), fg = sigf(p1), gg = tanh_f(p2), og = sigf(p3);
            c_state = fg * c_state + ig * gg;
            float h = og * tanh_f(c_state);
            hstage[bb * 8 + u] = f2bf(h);
        }
        __syncthreads();

        // ---- publish h slice: L2-bypass 8B stores -> LLC-coherent ----
        if (tid < 64) {
            int bb = tid >> 1, part = tid & 1;
            u64 q = *(u64*)(hstage + bb * 8 + part * 4);
            u64* dst = (u64*)(hall + ((size_t)(t + 1) * B_ + bb) * H_ + wg * 8 + part * 4);
            __hip_atomic_store(dst, q, __ATOMIC_RELAXED, __HIP_MEMORY_SCOPE_AGENT);
        }
        __syncthreads();   // drains vmcnt per thread -> all h stores at LLC
        if (tid == 0)
            __hip_atomic_store(flags + t * NWG + wg, 1u, __ATOMIC_RELAXED, __HIP_MEMORY_SCOPE_AGENT);
    }
}

// ---------------- output GEMMs: C[M x N] = A[M x 1024] * B[N x 1024]^T + bias ----------------
template<int PERM>
__global__ __launch_bounds__(256) void gemm_bt(
        const unsigned short* __restrict__ A,
        const unsigned short* __restrict__ Bw,
        const float* __restrict__ bias,
        float* __restrict__ out)
{
    __shared__ unsigned short As[128 * 64];
    __shared__ unsigned short Bs[128 * 64];
    const int tid  = threadIdx.x;
    const int lane = tid & 63, w = tid >> 6;
    const int wm = w >> 1, wn = w & 1;
    const int mbase = blockIdx.y * 128, nbase = blockIdx.x * 128;
    const int l15 = lane & 15, l4 = lane >> 4;

    f32x4 acc[4][4];
    #pragma unroll
    for (int i = 0; i < 4; i++)
        #pragma unroll
        for (int j = 0; j < 4; j++) acc[i][j] = (f32x4){0.f, 0.f, 0.f, 0.f};

    for (int kb = 0; kb < 16; kb++) {
        __syncthreads();
        #pragma unroll
        for (int i = 0; i < 4; i++) {
            int s = i * 256 + tid;
            int row = s >> 3, g = s & 7;
            int gd = g ^ (row & 7);
            int4 va = *(const int4*)(A  + (mbase + row) * 1024 + kb * 64 + g * 8);
            *(int4*)(As + row * 64 + gd * 8) = va;
            int4 vb = *(const int4*)(Bw + (nbase + row) * 1024 + kb * 64 + g * 8);
            *(int4*)(Bs + row * 64 + gd * 8) = vb;
        }
        __syncthreads();
        #pragma unroll
        for (int kk = 0; kk < 2; kk++) {
            bf16x8 af[4], bf[4];
            #pragma unroll
            for (int mt = 0; mt < 4; mt++) {
                int row = wm * 64 + mt * 16 + l15;
                int gg = (kk * 4 + l4) ^ (row & 7);
                af[mt] = *(const bf16x8*)(As + row * 64 + gg * 8);
            }
            #pragma unroll
            for (int nt = 0; nt < 4; nt++) {
                int row = wn * 64 + nt * 16 + l15;
                int gg = (kk * 4 + l4) ^ (row & 7);
                bf[nt] = *(const bf16x8*)(Bs + row * 64 + gg * 8);
            }
            #pragma unroll
            for (int mt = 0; mt < 4; mt++)
                #pragma unroll
                for (int nt = 0; nt < 4; nt++)
                    acc[mt][nt] = __builtin_amdgcn_mfma_f32_16x16x32_bf16(af[mt], bf[nt], acc[mt][nt], 0, 0, 0);
        }
    }
    #pragma unroll
    for (int mt = 0; mt < 4; mt++)
        #pragma unroll
        for (int nt = 0; nt < 4; nt++)
            #pragma unroll
            for (int r = 0; r < 4; r++) {
                int grow = mbase + wm * 64 + mt * 16 + l4 * 4 + r;
                int gcol = nbase + wn * 64 + nt * 16 + l15;
                float v = acc[mt][nt][r] + bias[gcol];
                int idx;
                if (PERM == 1) {
                    int tt = grow >> 5, bb = grow & 31;
                    idx = (bb * 1024 + tt) * 512 + gcol;
                } else {
                    idx = grow * 1024 + gcol;
                }
                out[idx] = v;
            }
}

// ---------------- host ----------------
extern "C" void kernel_launch(void* const* d_in, const int* in_sizes, int n_in,
                              void* d_out, int out_size, void* d_ws, size_t ws_size,
                              hipStream_t stream) {
    (void)in_sizes; (void)n_in; (void)out_size; (void)ws_size;
    const float* x    = (const float*)d_in[0];
    const float* Wih  = (const float*)d_in[1];
    const float* Whh  = (const float*)d_in[2];
    const float* bih  = (const float*)d_in[3];
    const float* bhh  = (const float*)d_in[4];
    const float* fcw  = (const float*)d_in[5];
    const float* fcb  = (const float*)d_in[6];
    const float* lnw  = (const float*)d_in[7];
    const float* lnb  = (const float*)d_in[8];
    float* out = (float*)d_out;

    char* ws = (char*)d_ws;
    size_t o = 0;
    unsigned short* whh_b = (unsigned short*)(ws + o); o += 8388608;   // [4096][1024]
    unsigned short* wih_b = (unsigned short*)(ws + o); o += 4194304;   // [4096][512]
    unsigned short* fcw_b = (unsigned short*)(ws + o); o += 1048576;   // [512][1024]
    unsigned short* lnw_b = (unsigned short*)(ws + o); o += 2097152;   // [1024][1024]
    unsigned short* x_b   = (unsigned short*)(ws + o); o += 33554432;  // [32][1024][512]
    float*          bias_c = (float*)(ws + o);         o += 16384;     // [4096]
    unsigned short* hall  = (unsigned short*)(ws + o); o += 67174400;  // [1025][32][1024]
    unsigned int*   flags = (unsigned int*)(ws + o);   o += 524288;    // [1024][128]

    hipMemsetAsync(flags, 0, 524288, stream);
    hipMemsetAsync(hall, 0, 65536, stream);      // h slot 0 = zeros

    cvt_kernel<<<4096,  256, 0, stream>>>(Whh, whh_b, 4194304 / 4);
    cvt_kernel<<<2048,  256, 0, stream>>>(Wih, wih_b, 2097152 / 4);
    cvt_kernel<<<512,   256, 0, stream>>>(fcw, fcw_b, 524288 / 4);
    cvt_kernel<<<1024,  256, 0, stream>>>(lnw, lnw_b, 1048576 / 4);
    cvt_kernel<<<16384, 256, 0, stream>>>(x,   x_b,   16777216 / 4);
    bias_kernel<<<16, 256, 0, stream>>>(bih, bhh, bias_c);

    const unsigned short* a0 = whh_b;
    const unsigned short* a1 = wih_b;
    const unsigned short* a2 = x_b;
    const float*          a3 = bias_c;
    unsigned short*       a4 = hall;
    unsigned int*         a5 = flags;
    void* args[6] = { (void*)&a0, (void*)&a1, (void*)&a2, (void*)&a3, (void*)&a4, (void*)&a5 };
    hipLaunchCooperativeKernel((void*)lstm_rec, dim3(NWG), dim3(512), args,
                               (unsigned)(98304 + 32768 + 128 + 512), stream);

    const unsigned short* hseq = hall + 32768;  // slot 1 = h at t=0
    gemm_bt<1><<<dim3(4, 256), 256, 0, stream>>>(hseq, fcw_b, fcb, out);
    gemm_bt<2><<<dim3(8, 256), 256, 0, stream>>>(hseq, lnw_b, lnb, out + 16777216);
}